// Round 12
// baseline (300.543 us; speedup 1.0000x reference)
//
#include <hip/hip_runtime.h>

typedef __attribute__((ext_vector_type(8))) __bf16 bf16x8;
typedef __attribute__((ext_vector_type(4))) float f32x4;

__device__ __forceinline__ float bf2f(unsigned int u) {
    return __uint_as_float(u << 16);
}
__device__ __forceinline__ unsigned short f2bf(float f) {
    unsigned int x = __float_as_uint(f);
    return (unsigned short)((x + 0x7fffu + ((x >> 16) & 1u)) >> 16);
}

// pack 2 bf16 products: low = bf16(e_lo*r_lo), high = bf16(e_hi*r_hi)
__device__ __forceinline__ unsigned int mulpack(unsigned int e, unsigned int r) {
    float e0 = __uint_as_float(e << 16);
    float e1 = __uint_as_float(e & 0xffff0000u);
    float r0 = __uint_as_float(r << 16);
    float r1 = __uint_as_float(r & 0xffff0000u);
    float p0 = e0 * r0;
    float p1 = e1 * r1;
    unsigned int out;
    asm("v_cvt_pk_bf16_f32 %0, %1, %2" : "=v"(out) : "v"(p0), "v"(p1));
    return out;
}

__device__ __forceinline__ bf16x8 mp4(uint4 e, uint4 r) {
    union { uint4 a; bf16x8 b; } u;
    u.a.x = mulpack(e.x, r.x);
    u.a.y = mulpack(e.y, r.y);
    u.a.z = mulpack(e.z, r.z);
    u.a.w = mulpack(e.w, r.w);
    return u.b;
}

// ---------------- merged cast f32 -> bf16 ----------------
__global__ void cast_all(const float* __restrict__ ent, const float* __restrict__ rel,
                         const float* __restrict__ W,
                         unsigned short* __restrict__ X_bf,
                         unsigned short* __restrict__ W_bf) {
    int i = blockIdx.x * blockDim.x + threadIdx.x;
    const float* src;
    unsigned short* dst;
    int g;
    if (i < 262144) {
        src = ent; dst = X_bf; g = i;
    } else if (i < 266240) {
        src = rel; dst = X_bf + 2048 * 512; g = i - 262144;
    } else {
        if (i >= 331776) return;
        src = W; dst = W_bf; g = i - 266240;
    }
    float4 v = reinterpret_cast<const float4*>(src)[g];
    ushort4 o;
    o.x = f2bf(v.x); o.y = f2bf(v.y); o.z = f2bf(v.z); o.w = f2bf(v.w);
    reinterpret_cast<ushort4*>(dst)[g] = o;
}

// ---------------- gate GEMM (m97 128^2 structure, known-good) ----------------
#define BM 128
#define BN 128
#define BK 64

template <bool GUARD_M, bool BIAS_BF16OUT>
__global__ __launch_bounds__(256, 2) void mfma_gemm_bt(
    const unsigned short* __restrict__ A,
    const unsigned short* __restrict__ Bt,
    const float* __restrict__ bias,
    void* __restrict__ Cout,
    int M, int N, int K) {
    __shared__ __align__(16) unsigned short As[BM * BK];
    __shared__ __align__(16) unsigned short Bs[BN * BK];

    const int tid = threadIdx.x;
    const int lane = tid & 63;
    const int wave = tid >> 6;
    const int nbn = N / BN;
    const int bm0 = (blockIdx.x / nbn) * BM;
    const int bn0 = (blockIdx.x % nbn) * BN;
    const int wr = wave >> 1, wc = wave & 1;

    f32x4 acc[4][4] = {};

    const int srow = wave * 32 + (lane >> 3);
    const int scol = (lane & 7) * 8;

    for (int kb = 0; kb < K; kb += BK) {
#pragma unroll
        for (int i = 0; i < 4; ++i) {
            int row = bm0 + srow + i * 8;
            if (GUARD_M) row = min(row, M - 1);
            const unsigned short* src = A + (size_t)row * K + kb + scol;
            unsigned short* dst = &As[(wave * 32 + i * 8) * BK];
            __builtin_amdgcn_global_load_lds(
                (const __attribute__((address_space(1))) void*)src,
                (__attribute__((address_space(3))) void*)dst, 16, 0, 0);
        }
#pragma unroll
        for (int i = 0; i < 4; ++i) {
            int row = bn0 + srow + i * 8;
            const unsigned short* src = Bt + (size_t)row * K + kb + scol;
            unsigned short* dst = &Bs[(wave * 32 + i * 8) * BK];
            __builtin_amdgcn_global_load_lds(
                (const __attribute__((address_space(1))) void*)src,
                (__attribute__((address_space(3))) void*)dst, 16, 0, 0);
        }
        __syncthreads();

#pragma unroll
        for (int ks = 0; ks < BK / 32; ++ks) {
            const int k0 = ks * 32 + (lane >> 4) * 8;
            bf16x8 av[4], bv[4];
#pragma unroll
            for (int m = 0; m < 4; ++m)
                av[m] = *reinterpret_cast<const bf16x8*>(
                    &As[(wr * 64 + m * 16 + (lane & 15)) * BK + k0]);
#pragma unroll
            for (int n = 0; n < 4; ++n)
                bv[n] = *reinterpret_cast<const bf16x8*>(
                    &Bs[(wc * 64 + n * 16 + (lane & 15)) * BK + k0]);
#pragma unroll
            for (int m = 0; m < 4; ++m)
#pragma unroll
                for (int n = 0; n < 4; ++n)
                    acc[m][n] = __builtin_amdgcn_mfma_f32_16x16x32_bf16(
                        av[m], bv[n], acc[m][n], 0, 0, 0);
        }
        __syncthreads();
    }

#pragma unroll
    for (int m = 0; m < 4; ++m) {
#pragma unroll
        for (int n = 0; n < 4; ++n) {
#pragma unroll
            for (int j = 0; j < 4; ++j) {
                int row = bm0 + wr * 64 + m * 16 + (lane >> 4) * 4 + j;
                int col = bn0 + wc * 64 + n * 16 + (lane & 15);
                if (GUARD_M && row >= M) continue;
                float v = acc[m][n][j];
                if (BIAS_BF16OUT) {
                    v += bias[col];
                    ((unsigned short*)Cout)[(size_t)row * N + col] = f2bf(v);
                } else {
                    ((float*)Cout)[(size_t)row * N + col] = v;
                }
            }
        }
    }
}

// ---------------- main GEMM: 128x256 tile, BK=32, FUSED in-register A ----------
// C[er][f] = sum_k E[er>>5][k]*R[er&31][k] * E[f][k]  -- A' built in registers:
// per lane av[m] needs only E[e] (quad-uniform, e = bm0/32+wr*2+(m>>1)) and
// R[r] (r = (m&1)*16+laneM): 2 E + 2 R b128 loads/tile/lane from L1/L2-hot G.
// LDS: B-only triple buffer (3 x 16KB). Single barrier per tile. vmcnt(6) counted
// (2 stage + 4 ER in flight). Epilogue: R10's LDS transpose + nt 256B-chunk stores.
#define NT16 16  // K / 32

__global__ __launch_bounds__(512) void gemm_fusedA(
    const unsigned short* __restrict__ G,  // [2080][512]: rows 0..2047=E, 2048..2079=R
    float* __restrict__ C) {
    __shared__ __align__(16) unsigned short lds16[32768];  // 64 KiB

    const int tid = threadIdx.x;
    const int lane = tid & 63;
    const int wave = tid >> 6;   // 0..7
    const int wr = wave >> 2;    // 0..1 -> er 64-half
    const int wc = wave & 3;     // 0..3 -> f 64-quarter
    const int laneM = lane & 15;
    const int q = lane >> 4;
    const int laneK = q * 8;

    // XCD swizzle: 4096 blocks = 8 x 512; per XCD: 64 bm-tiles x 8 bn
    const int swz = (blockIdx.x & 7) * 512 + (blockIdx.x >> 3);
    const int bm0 = (swz >> 3) * 128;
    const int bn0 = (swz & 7) * 256;

    // B staging: linear LDS dest, pre-swizzled global source
    const int sr = tid >> 2;                            // row 0..127 within unit
    const int scs = ((tid & 3) * 8) ^ ((sr & 3) * 8);

    auto STAGE_B = [&](int kb, int P) {
#pragma unroll
        for (int rd = 0; rd < 2; ++rd) {
            const unsigned short* src =
                G + (size_t)(bn0 + rd * 128 + sr) * 512 + kb + scs;
            __builtin_amdgcn_global_load_lds(
                (const __attribute__((address_space(1))) void*)src,
                (__attribute__((address_space(3))) void*)
                    &lds16[P * 8192 + rd * 4096 + wave * 512],
                16, 0, 0);
        }
    };
    auto RD = [&](int P, int rr) -> bf16x8 {
        return *reinterpret_cast<const bf16x8*>(
            &lds16[P * 8192 + rr * 32 + (laneK ^ ((rr & 3) * 8))]);
    };

    // ER pointers: e = bm0/32 + wr*2 + h (h=m>>1, uniform per 16-lane group);
    //              r = (m&1)*16 + laneM
    const unsigned short* Eb = G + (size_t)((bm0 >> 5) + wr * 2) * 512 + laneK;
    const unsigned short* Rb = G + (size_t)(2048 + laneM) * 512 + laneK;

    uint4 Ev[2][2], Rv[2][2];  // [t&1][h]
    auto ISSUE_ER = [&](int t) {
        const int p = t & 1;
#pragma unroll
        for (int h = 0; h < 2; ++h) {
            Ev[p][h] = *reinterpret_cast<const uint4*>(Eb + h * 512 + t * 32);
            Rv[p][h] = *reinterpret_cast<const uint4*>(Rb + h * 16 * 512 + t * 32);
        }
    };

    f32x4 acc[4][4] = {};
    bf16x8 bv[4];

    // ===== prologue =====
    ISSUE_ER(0);
    STAGE_B(0, 0);
    STAGE_B(32, 1);
    asm volatile("s_waitcnt vmcnt(2)" ::: "memory");  // ER(0)+B(0) done, B(1) in flight
    __builtin_amdgcn_s_barrier();

#pragma unroll
    for (int t = 0; t < NT16; ++t) {
        const int P = t % 3;

        // reads: 4 bv fragments from buf(t)
#pragma unroll
        for (int n = 0; n < 4; ++n)
            bv[n] = RD(P, wc * 64 + n * 16 + laneM);

        // stage B(t+2); issue ER(t+1)
        if (t + 2 < NT16)
            STAGE_B((t + 2) * 32, (t + 2) % 3);
        if (t + 1 < NT16)
            ISSUE_ER(t + 1);

        asm volatile("s_waitcnt lgkmcnt(0)" ::: "memory");
        __builtin_amdgcn_sched_barrier(0);

        // build av per m (compiler inserts vmcnt for ER(t)) and MFMA
        __builtin_amdgcn_s_setprio(1);
#pragma unroll
        for (int m = 0; m < 4; ++m) {
            bf16x8 av = mp4(Ev[t & 1][m >> 1], Rv[t & 1][m & 1]);
#pragma unroll
            for (int n = 0; n < 4; ++n)
                acc[m][n] = __builtin_amdgcn_mfma_f32_16x16x32_bf16(
                    av, bv[n], acc[m][n], 0, 0, 0);
        }
        __builtin_amdgcn_s_setprio(0);

        if (t < NT16 - 1) {
            if (t < NT16 - 2)
                asm volatile("s_waitcnt vmcnt(6)" ::: "memory");
            else
                asm volatile("s_waitcnt vmcnt(4)" ::: "memory");
            __builtin_amdgcn_s_barrier();
        }
    }

    // ===== epilogue: LDS transpose -> nt f32x4 stores (256B x 4-row chunks) =====
    // acc C/D: er = bm0 + wr*64 + m*16 + q*4 + j ; f = bn0 + wc*64 + n*16 + laneM
    {
        float* fb = (float*)lds16;
#pragma unroll
        for (int p = 0; p < 2; ++p) {
            __syncthreads();
            if (wr == p) {
#pragma unroll
                for (int m = 0; m < 4; ++m)
#pragma unroll
                    for (int n = 0; n < 4; ++n)
#pragma unroll
                        for (int j = 0; j < 4; ++j) {
                            int L = m * 16 + q * 4 + j;
                            int fl = wc * 64 + n * 16 + laneM;
                            fb[L * 256 + (fl ^ ((L & 12) << 2))] = acc[m][n][j];
                        }
            }
            __syncthreads();
#pragma unroll
            for (int rr = 0; rr < 2; ++rr) {
                int R = wave * 8 + rr * 4 + q;
                float* dstRow = C + (size_t)(bm0 + p * 64 + R) * 2048 + bn0;
                int sx = (R & 12) << 2;
#pragma unroll
                for (int g = 0; g < 4; ++g) {
                    int fl = g * 64 + laneM * 4;
                    f32x4 v = *reinterpret_cast<const f32x4*>(
                        &fb[R * 256 + (fl ^ sx)]);
                    __builtin_nontemporal_store(v, (f32x4*)(dstRow + fl));
                }
            }
        }
    }
}

// ---------------- launcher ----------------
extern "C" void kernel_launch(void* const* d_in, const int* in_sizes, int n_in,
                              void* d_out, int out_size, void* d_ws, size_t ws_size,
                              hipStream_t stream) {
    const float* entities  = (const float*)d_in[0];
    const float* relations = (const float*)d_in[1];
    const float* W         = (const float*)d_in[2];
    const float* b         = (const float*)d_in[3];

    char* ws = (char*)d_ws;
    unsigned short* W_bf = (unsigned short*)ws;
    unsigned short* X_bf = (unsigned short*)(ws + 524288);
    unsigned short* G_bf = (unsigned short*)(ws + 524288 + 2129920);

    cast_all<<<1296, 256, 0, stream>>>(entities, relations, W, X_bf, W_bf);

    // gate GEMM: G[2080][512] = X @ W^T + b  (bf16 out)
    mfma_gemm_bt<true, true><<<17 * 4, 256, 0, stream>>>(
        X_bf, W_bf, b, (void*)G_bf, 2080, 512, 512);

    // main: fused-A GEMM, out[65536][2048] (128x256 tiles)
    gemm_fusedA<<<4096, 512, 0, stream>>>(G_bf, (float*)d_out);
}

// Round 13
// 202.478 us; speedup vs baseline: 1.4843x; 1.4843x over previous
//
#include <hip/hip_runtime.h>

typedef __attribute__((ext_vector_type(8))) __bf16 bf16x8;
typedef __attribute__((ext_vector_type(4))) float f32x4;

__device__ __forceinline__ float bf2f(unsigned int u) {
    return __uint_as_float(u << 16);
}
__device__ __forceinline__ unsigned short f2bf(float f) {
    unsigned int x = __float_as_uint(f);
    return (unsigned short)((x + 0x7fffu + ((x >> 16) & 1u)) >> 16);
}

// ---------------- merged cast f32 -> bf16 ----------------
__global__ void cast_all(const float* __restrict__ ent, const float* __restrict__ rel,
                         const float* __restrict__ W,
                         unsigned short* __restrict__ X_bf,
                         unsigned short* __restrict__ W_bf) {
    int i = blockIdx.x * blockDim.x + threadIdx.x;
    const float* src;
    unsigned short* dst;
    int g;
    if (i < 262144) {
        src = ent; dst = X_bf; g = i;
    } else if (i < 266240) {
        src = rel; dst = X_bf + 2048 * 512; g = i - 262144;
    } else {
        if (i >= 331776) return;
        src = W; dst = W_bf; g = i - 266240;
    }
    float4 v = reinterpret_cast<const float4*>(src)[g];
    ushort4 o;
    o.x = f2bf(v.x); o.y = f2bf(v.y); o.z = f2bf(v.z); o.w = f2bf(v.w);
    reinterpret_cast<ushort4*>(dst)[g] = o;
}

// ---------------- A'[(e*32+r), d] = E[e,d] * R[r,d] (er-major) ----------------
__device__ __forceinline__ unsigned int mul2bf(unsigned int a, unsigned int b) {
    float a0 = bf2f(a & 0xffffu), a1 = bf2f(a >> 16);
    float b0 = bf2f(b & 0xffffu), b1 = bf2f(b >> 16);
    return (unsigned int)f2bf(a0 * b0) | ((unsigned int)f2bf(a1 * b1) << 16);
}

__global__ void build_ap(const unsigned short* __restrict__ G,
                         unsigned short* __restrict__ Ap) {
    int t = blockIdx.x * blockDim.x + threadIdx.x;
    int row = t >> 6;
    int d = (t & 63) * 8;
    int e = row >> 5, r = row & 31;
    const uint4 ev = *reinterpret_cast<const uint4*>(G + e * 512 + d);
    const uint4 rv = *reinterpret_cast<const uint4*>(G + (2048 + r) * 512 + d);
    uint4 o;
    o.x = mul2bf(ev.x, rv.x);
    o.y = mul2bf(ev.y, rv.y);
    o.z = mul2bf(ev.z, rv.z);
    o.w = mul2bf(ev.w, rv.w);
    *reinterpret_cast<uint4*>(Ap + (size_t)row * 512 + d) = o;
}

// ---------------- gate GEMM (m97 128^2 structure, known-good) ----------------
#define BM 128
#define BN 128
#define BK 64

template <bool GUARD_M, bool BIAS_BF16OUT>
__global__ __launch_bounds__(256, 2) void mfma_gemm_bt(
    const unsigned short* __restrict__ A,
    const unsigned short* __restrict__ Bt,
    const float* __restrict__ bias,
    void* __restrict__ Cout,
    int M, int N, int K) {
    __shared__ __align__(16) unsigned short As[BM * BK];
    __shared__ __align__(16) unsigned short Bs[BN * BK];

    const int tid = threadIdx.x;
    const int lane = tid & 63;
    const int wave = tid >> 6;
    const int nbn = N / BN;
    const int bm0 = (blockIdx.x / nbn) * BM;
    const int bn0 = (blockIdx.x % nbn) * BN;
    const int wr = wave >> 1, wc = wave & 1;

    f32x4 acc[4][4] = {};

    const int srow = wave * 32 + (lane >> 3);
    const int scol = (lane & 7) * 8;

    for (int kb = 0; kb < K; kb += BK) {
#pragma unroll
        for (int i = 0; i < 4; ++i) {
            int row = bm0 + srow + i * 8;
            if (GUARD_M) row = min(row, M - 1);
            const unsigned short* src = A + (size_t)row * K + kb + scol;
            unsigned short* dst = &As[(wave * 32 + i * 8) * BK];
            __builtin_amdgcn_global_load_lds(
                (const __attribute__((address_space(1))) void*)src,
                (__attribute__((address_space(3))) void*)dst, 16, 0, 0);
        }
#pragma unroll
        for (int i = 0; i < 4; ++i) {
            int row = bn0 + srow + i * 8;
            const unsigned short* src = Bt + (size_t)row * K + kb + scol;
            unsigned short* dst = &Bs[(wave * 32 + i * 8) * BK];
            __builtin_amdgcn_global_load_lds(
                (const __attribute__((address_space(1))) void*)src,
                (__attribute__((address_space(3))) void*)dst, 16, 0, 0);
        }
        __syncthreads();

#pragma unroll
        for (int ks = 0; ks < BK / 32; ++ks) {
            const int k0 = ks * 32 + (lane >> 4) * 8;
            bf16x8 av[4], bv[4];
#pragma unroll
            for (int m = 0; m < 4; ++m)
                av[m] = *reinterpret_cast<const bf16x8*>(
                    &As[(wr * 64 + m * 16 + (lane & 15)) * BK + k0]);
#pragma unroll
            for (int n = 0; n < 4; ++n)
                bv[n] = *reinterpret_cast<const bf16x8*>(
                    &Bs[(wc * 64 + n * 16 + (lane & 15)) * BK + k0]);
#pragma unroll
            for (int m = 0; m < 4; ++m)
#pragma unroll
                for (int n = 0; n < 4; ++n)
                    acc[m][n] = __builtin_amdgcn_mfma_f32_16x16x32_bf16(
                        av[m], bv[n], acc[m][n], 0, 0, 0);
        }
        __syncthreads();
    }

#pragma unroll
    for (int m = 0; m < 4; ++m) {
#pragma unroll
        for (int n = 0; n < 4; ++n) {
#pragma unroll
            for (int j = 0; j < 4; ++j) {
                int row = bm0 + wr * 64 + m * 16 + (lane >> 4) * 4 + j;
                int col = bn0 + wc * 64 + n * 16 + (lane & 15);
                if (GUARD_M && row >= M) continue;
                float v = acc[m][n][j];
                if (BIAS_BF16OUT) {
                    v += bias[col];
                    ((unsigned short*)Cout)[(size_t)row * N + col] = f2bf(v);
                } else {
                    ((float*)Cout)[(size_t)row * N + col] = v;
                }
            }
        }
    }
}

// ---------------- main GEMM: 128x256, BK=32, triple-buffer, 1 barrier/tile ----
// C[65536][2048] = A'[65536][512] @ E[2048][512]^T
// Single variable vs round 10: the 3-barrier phase split is collapsed to
// {read 8 frags | stage 3 units | lgkmcnt(0) | 16 MFMA | vmcnt(3) | barrier}.
// Epilogue: LDS transpose -> nt f32x4 stores (256B x 4-row chunks), as round 10.
#define NT16 16  // K / 32

__global__ __launch_bounds__(512, 4) void gemm128x256(
    const unsigned short* __restrict__ A,  // [65536][512]
    const unsigned short* __restrict__ B,  // [2048][512]
    float* __restrict__ C) {
    __shared__ __align__(16) unsigned short lds16[36864];  // 72 KiB

    const int tid = threadIdx.x;
    const int lane = tid & 63;
    const int wave = tid >> 6;   // 0..7
    const int wr = wave >> 2;    // 0..1 -> er 64-half
    const int wc = wave & 3;     // 0..3 -> f 64-quarter
    const int laneM = lane & 15;
    const int q = lane >> 4;
    const int laneK = q * 8;

    // XCD swizzle: 4096 blocks = 8 x 512; per XCD: 64 bm-tiles x 8 bn -> A L2-shared
    const int swz = (blockIdx.x & 7) * 512 + (blockIdx.x >> 3);
    const int bm0 = (swz >> 3) * 128;
    const int bn0 = (swz & 7) * 256;

    // staging: unit 8KB = 128 rows x 32k bf16 = 512 threads x 16B (one gload each)
    const int sr = tid >> 2;                            // row 0..127
    const int scs = ((tid & 3) * 8) ^ ((sr & 3) * 8);   // pre-swizzled col (elems)

    auto STAGE = [&](const unsigned short* mat, int row0, int kb, int slotU) {
        const unsigned short* src = mat + (size_t)(row0 + sr) * 512 + kb + scs;
        __builtin_amdgcn_global_load_lds(
            (const __attribute__((address_space(1))) void*)src,
            (__attribute__((address_space(3))) void*)&lds16[slotU + wave * 512],
            16, 0, 0);
    };
    // buffer P: base P*12288; A rows [0,128) at +0; B rows [0,256) at +4096
    auto RD = [&](int base, int rr) -> bf16x8 {
        return *reinterpret_cast<const bf16x8*>(
            &lds16[base + rr * 32 + (laneK ^ ((rr & 3) * 8))]);
    };

    f32x4 acc[4][4] = {};
    bf16x8 av[4], bv[4];

    // prologue: stage tiles 0 and 1
    STAGE(A, bm0,        0, 0);
    STAGE(B, bn0,        0, 4096);
    STAGE(B, bn0 + 128,  0, 8192);
    STAGE(A, bm0,       32, 12288);
    STAGE(B, bn0,       32, 12288 + 4096);
    STAGE(B, bn0 + 128, 32, 12288 + 8192);
    asm volatile("s_waitcnt vmcnt(3)" ::: "memory");
    __builtin_amdgcn_s_barrier();

#pragma unroll
    for (int t = 0; t < NT16; ++t) {
        const int base = (t % 3) * 12288;
        const int nb = ((t + 2) % 3) * 12288;

        // read all 8 fragments
#pragma unroll
        for (int m = 0; m < 4; ++m)
            av[m] = RD(base, wr * 64 + m * 16 + laneM);
#pragma unroll
        for (int n = 0; n < 4; ++n)
            bv[n] = RD(base + 4096, wc * 64 + n * 16 + laneM);

        // stage tile t+2 (3 units)
        if (t + 2 < NT16) {
            STAGE(A, bm0, (t + 2) * 32, nb);
            STAGE(B, bn0, (t + 2) * 32, nb + 4096);
            STAGE(B, bn0 + 128, (t + 2) * 32, nb + 8192);
        }

        asm volatile("s_waitcnt lgkmcnt(0)" ::: "memory");
        __builtin_amdgcn_sched_barrier(0);
        __builtin_amdgcn_s_setprio(1);
#pragma unroll
        for (int m = 0; m < 4; ++m)
#pragma unroll
            for (int n = 0; n < 4; ++n)
                acc[m][n] = __builtin_amdgcn_mfma_f32_16x16x32_bf16(
                    av[m], bv[n], acc[m][n], 0, 0, 0);
        __builtin_amdgcn_s_setprio(0);

        if (t < NT16 - 1) {
            if (t == NT16 - 2)
                asm volatile("s_waitcnt vmcnt(0)" ::: "memory");
            else
                asm volatile("s_waitcnt vmcnt(3)" ::: "memory");
            __builtin_amdgcn_s_barrier();
        }
    }

    // ===== epilogue: LDS transpose -> nt f32x4 stores (256B x 4-row chunks) =====
    // acc C/D: er = bm0 + wr*64 + m*16 + q*4 + j ; f = bn0 + wc*64 + n*16 + laneM
    {
        float* fb = (float*)lds16;
#pragma unroll
        for (int p = 0; p < 2; ++p) {
            __syncthreads();
            if (wr == p) {
#pragma unroll
                for (int m = 0; m < 4; ++m)
#pragma unroll
                    for (int n = 0; n < 4; ++n)
#pragma unroll
                        for (int j = 0; j < 4; ++j) {
                            int L = m * 16 + q * 4 + j;
                            int fl = wc * 64 + n * 16 + laneM;
                            fb[L * 256 + (fl ^ ((L & 12) << 2))] = acc[m][n][j];
                        }
            }
            __syncthreads();
#pragma unroll
            for (int rr = 0; rr < 2; ++rr) {
                int R = wave * 8 + rr * 4 + q;
                float* dstRow = C + (size_t)(bm0 + p * 64 + R) * 2048 + bn0;
                int sx = (R & 12) << 2;
#pragma unroll
                for (int g = 0; g < 4; ++g) {
                    int fl = g * 64 + laneM * 4;
                    f32x4 v = *reinterpret_cast<const f32x4*>(
                        &fb[R * 256 + (fl ^ sx)]);
                    __builtin_nontemporal_store(v, (f32x4*)(dstRow + fl));
                }
            }
        }
    }
}

// ---------------- launcher ----------------
extern "C" void kernel_launch(void* const* d_in, const int* in_sizes, int n_in,
                              void* d_out, int out_size, void* d_ws, size_t ws_size,
                              hipStream_t stream) {
    const float* entities  = (const float*)d_in[0];
    const float* relations = (const float*)d_in[1];
    const float* W         = (const float*)d_in[2];
    const float* b         = (const float*)d_in[3];

    char* ws = (char*)d_ws;
    unsigned short* W_bf = (unsigned short*)ws;
    unsigned short* X_bf = (unsigned short*)(ws + 524288);
    unsigned short* G_bf = (unsigned short*)(ws + 524288 + 2129920);
    unsigned short* Ap   = (unsigned short*)(ws + 524288 + 2129920 + 2129920);

    cast_all<<<1296, 256, 0, stream>>>(entities, relations, W, X_bf, W_bf);

    // gate GEMM: G[2080][512] = X @ W^T + b  (bf16 out)
    mfma_gemm_bt<true, true><<<17 * 4, 256, 0, stream>>>(
        X_bf, W_bf, b, (void*)G_bf, 2080, 512, 512);

    // A'[(e*32+r), d] = E[e,d] * R[r,d]
    build_ap<<<16384, 256, 0, stream>>>(G_bf, Ap);

    // main GEMM: out[65536][2048] = A' @ E^T  (128x256 tiles, 2 blocks/CU)
    gemm128x256<<<4096, 512, 0, stream>>>(Ap, G_bf, (float*)d_out);
}

// Round 14
// 202.315 us; speedup vs baseline: 1.4855x; 1.0008x over previous
//
#include <hip/hip_runtime.h>

typedef __attribute__((ext_vector_type(8))) __bf16 bf16x8;
typedef __attribute__((ext_vector_type(4))) float f32x4;

__device__ __forceinline__ float bf2f(unsigned int u) {
    return __uint_as_float(u << 16);
}
__device__ __forceinline__ unsigned short f2bf(float f) {
    unsigned int x = __float_as_uint(f);
    return (unsigned short)((x + 0x7fffu + ((x >> 16) & 1u)) >> 16);
}

// ---------------- merged cast f32 -> bf16 ----------------
__global__ void cast_all(const float* __restrict__ ent, const float* __restrict__ rel,
                         const float* __restrict__ W,
                         unsigned short* __restrict__ X_bf,
                         unsigned short* __restrict__ W_bf) {
    int i = blockIdx.x * blockDim.x + threadIdx.x;
    const float* src;
    unsigned short* dst;
    int g;
    if (i < 262144) {
        src = ent; dst = X_bf; g = i;
    } else if (i < 266240) {
        src = rel; dst = X_bf + 2048 * 512; g = i - 262144;
    } else {
        if (i >= 331776) return;
        src = W; dst = W_bf; g = i - 266240;
    }
    float4 v = reinterpret_cast<const float4*>(src)[g];
    ushort4 o;
    o.x = f2bf(v.x); o.y = f2bf(v.y); o.z = f2bf(v.z); o.w = f2bf(v.w);
    reinterpret_cast<ushort4*>(dst)[g] = o;
}

// ---------------- A'[(e*32+r), d] = E[e,d] * R[r,d] (er-major) ----------------
__device__ __forceinline__ unsigned int mul2bf(unsigned int a, unsigned int b) {
    float a0 = bf2f(a & 0xffffu), a1 = bf2f(a >> 16);
    float b0 = bf2f(b & 0xffffu), b1 = bf2f(b >> 16);
    return (unsigned int)f2bf(a0 * b0) | ((unsigned int)f2bf(a1 * b1) << 16);
}

__global__ void build_ap(const unsigned short* __restrict__ G,
                         unsigned short* __restrict__ Ap) {
    int t = blockIdx.x * blockDim.x + threadIdx.x;
    int row = t >> 6;
    int d = (t & 63) * 8;
    int e = row >> 5, r = row & 31;
    const uint4 ev = *reinterpret_cast<const uint4*>(G + e * 512 + d);
    const uint4 rv = *reinterpret_cast<const uint4*>(G + (2048 + r) * 512 + d);
    uint4 o;
    o.x = mul2bf(ev.x, rv.x);
    o.y = mul2bf(ev.y, rv.y);
    o.z = mul2bf(ev.z, rv.z);
    o.w = mul2bf(ev.w, rv.w);
    *reinterpret_cast<uint4*>(Ap + (size_t)row * 512 + d) = o;
}

// ---------------- gate GEMM (m97 128^2 structure, known-good) ----------------
#define BM 128
#define BN 128
#define BK 64

template <bool GUARD_M, bool BIAS_BF16OUT>
__global__ __launch_bounds__(256, 2) void mfma_gemm_bt(
    const unsigned short* __restrict__ A,
    const unsigned short* __restrict__ Bt,
    const float* __restrict__ bias,
    void* __restrict__ Cout,
    int M, int N, int K) {
    __shared__ __align__(16) unsigned short As[BM * BK];
    __shared__ __align__(16) unsigned short Bs[BN * BK];

    const int tid = threadIdx.x;
    const int lane = tid & 63;
    const int wave = tid >> 6;
    const int nbn = N / BN;
    const int bm0 = (blockIdx.x / nbn) * BM;
    const int bn0 = (blockIdx.x % nbn) * BN;
    const int wr = wave >> 1, wc = wave & 1;

    f32x4 acc[4][4] = {};

    const int srow = wave * 32 + (lane >> 3);
    const int scol = (lane & 7) * 8;

    for (int kb = 0; kb < K; kb += BK) {
#pragma unroll
        for (int i = 0; i < 4; ++i) {
            int row = bm0 + srow + i * 8;
            if (GUARD_M) row = min(row, M - 1);
            const unsigned short* src = A + (size_t)row * K + kb + scol;
            unsigned short* dst = &As[(wave * 32 + i * 8) * BK];
            __builtin_amdgcn_global_load_lds(
                (const __attribute__((address_space(1))) void*)src,
                (__attribute__((address_space(3))) void*)dst, 16, 0, 0);
        }
#pragma unroll
        for (int i = 0; i < 4; ++i) {
            int row = bn0 + srow + i * 8;
            const unsigned short* src = Bt + (size_t)row * K + kb + scol;
            unsigned short* dst = &Bs[(wave * 32 + i * 8) * BK];
            __builtin_amdgcn_global_load_lds(
                (const __attribute__((address_space(1))) void*)src,
                (__attribute__((address_space(3))) void*)dst, 16, 0, 0);
        }
        __syncthreads();

#pragma unroll
        for (int ks = 0; ks < BK / 32; ++ks) {
            const int k0 = ks * 32 + (lane >> 4) * 8;
            bf16x8 av[4], bv[4];
#pragma unroll
            for (int m = 0; m < 4; ++m)
                av[m] = *reinterpret_cast<const bf16x8*>(
                    &As[(wr * 64 + m * 16 + (lane & 15)) * BK + k0]);
#pragma unroll
            for (int n = 0; n < 4; ++n)
                bv[n] = *reinterpret_cast<const bf16x8*>(
                    &Bs[(wc * 64 + n * 16 + (lane & 15)) * BK + k0]);
#pragma unroll
            for (int m = 0; m < 4; ++m)
#pragma unroll
                for (int n = 0; n < 4; ++n)
                    acc[m][n] = __builtin_amdgcn_mfma_f32_16x16x32_bf16(
                        av[m], bv[n], acc[m][n], 0, 0, 0);
        }
        __syncthreads();
    }

#pragma unroll
    for (int m = 0; m < 4; ++m) {
#pragma unroll
        for (int n = 0; n < 4; ++n) {
#pragma unroll
            for (int j = 0; j < 4; ++j) {
                int row = bm0 + wr * 64 + m * 16 + (lane >> 4) * 4 + j;
                int col = bn0 + wc * 64 + n * 16 + (lane & 15);
                if (GUARD_M && row >= M) continue;
                float v = acc[m][n][j];
                if (BIAS_BF16OUT) {
                    v += bias[col];
                    ((unsigned short*)Cout)[(size_t)row * N + col] = f2bf(v);
                } else {
                    ((float*)Cout)[(size_t)row * N + col] = v;
                }
            }
        }
    }
}

// ---------------- main GEMM: 128x256, BK=32, triple-buffer, 1 barrier/tile ----
// C[65536][2048] = A'[65536][512] @ E[2048][512]^T
// Single variable vs round 13: epilogue nt stores emit ONE 1KB-contiguous row
// segment per wave-instruction (was 4 rows x 256B segments).
#define NT16 16  // K / 32

__global__ __launch_bounds__(512, 4) void gemm128x256(
    const unsigned short* __restrict__ A,  // [65536][512]
    const unsigned short* __restrict__ B,  // [2048][512]
    float* __restrict__ C) {
    __shared__ __align__(16) unsigned short lds16[36864];  // 72 KiB

    const int tid = threadIdx.x;
    const int lane = tid & 63;
    const int wave = tid >> 6;   // 0..7
    const int wr = wave >> 2;    // 0..1 -> er 64-half
    const int wc = wave & 3;     // 0..3 -> f 64-quarter
    const int laneM = lane & 15;
    const int q = lane >> 4;
    const int laneK = q * 8;

    // XCD swizzle: 4096 blocks = 8 x 512; per XCD: 64 bm-tiles x 8 bn -> A L2-shared
    const int swz = (blockIdx.x & 7) * 512 + (blockIdx.x >> 3);
    const int bm0 = (swz >> 3) * 128;
    const int bn0 = (swz & 7) * 256;

    // staging: unit 8KB = 128 rows x 32k bf16 = 512 threads x 16B (one gload each)
    const int sr = tid >> 2;                            // row 0..127
    const int scs = ((tid & 3) * 8) ^ ((sr & 3) * 8);   // pre-swizzled col (elems)

    auto STAGE = [&](const unsigned short* mat, int row0, int kb, int slotU) {
        const unsigned short* src = mat + (size_t)(row0 + sr) * 512 + kb + scs;
        __builtin_amdgcn_global_load_lds(
            (const __attribute__((address_space(1))) void*)src,
            (__attribute__((address_space(3))) void*)&lds16[slotU + wave * 512],
            16, 0, 0);
    };
    // buffer P: base P*12288; A rows [0,128) at +0; B rows [0,256) at +4096
    auto RD = [&](int base, int rr) -> bf16x8 {
        return *reinterpret_cast<const bf16x8*>(
            &lds16[base + rr * 32 + (laneK ^ ((rr & 3) * 8))]);
    };

    f32x4 acc[4][4] = {};
    bf16x8 av[4], bv[4];

    // prologue: stage tiles 0 and 1
    STAGE(A, bm0,        0, 0);
    STAGE(B, bn0,        0, 4096);
    STAGE(B, bn0 + 128,  0, 8192);
    STAGE(A, bm0,       32, 12288);
    STAGE(B, bn0,       32, 12288 + 4096);
    STAGE(B, bn0 + 128, 32, 12288 + 8192);
    asm volatile("s_waitcnt vmcnt(3)" ::: "memory");
    __builtin_amdgcn_s_barrier();

#pragma unroll
    for (int t = 0; t < NT16; ++t) {
        const int base = (t % 3) * 12288;
        const int nb = ((t + 2) % 3) * 12288;

        // read all 8 fragments
#pragma unroll
        for (int m = 0; m < 4; ++m)
            av[m] = RD(base, wr * 64 + m * 16 + laneM);
#pragma unroll
        for (int n = 0; n < 4; ++n)
            bv[n] = RD(base + 4096, wc * 64 + n * 16 + laneM);

        // stage tile t+2 (3 units)
        if (t + 2 < NT16) {
            STAGE(A, bm0, (t + 2) * 32, nb);
            STAGE(B, bn0, (t + 2) * 32, nb + 4096);
            STAGE(B, bn0 + 128, (t + 2) * 32, nb + 8192);
        }

        asm volatile("s_waitcnt lgkmcnt(0)" ::: "memory");
        __builtin_amdgcn_sched_barrier(0);
        __builtin_amdgcn_s_setprio(1);
#pragma unroll
        for (int m = 0; m < 4; ++m)
#pragma unroll
            for (int n = 0; n < 4; ++n)
                acc[m][n] = __builtin_amdgcn_mfma_f32_16x16x32_bf16(
                    av[m], bv[n], acc[m][n], 0, 0, 0);
        __builtin_amdgcn_s_setprio(0);

        if (t < NT16 - 1) {
            if (t == NT16 - 2)
                asm volatile("s_waitcnt vmcnt(0)" ::: "memory");
            else
                asm volatile("s_waitcnt vmcnt(3)" ::: "memory");
            __builtin_amdgcn_s_barrier();
        }
    }

    // ===== epilogue: LDS transpose -> nt f32x4 stores, 1KB contiguous/instr =====
    // acc C/D: er = bm0 + wr*64 + m*16 + q*4 + j ; f = bn0 + wc*64 + n*16 + laneM
    {
        float* fb = (float*)lds16;
        const int l4 = lane * 4;
#pragma unroll
        for (int p = 0; p < 2; ++p) {
            __syncthreads();
            if (wr == p) {
#pragma unroll
                for (int m = 0; m < 4; ++m)
#pragma unroll
                    for (int n = 0; n < 4; ++n)
#pragma unroll
                        for (int j = 0; j < 4; ++j) {
                            int L = m * 16 + q * 4 + j;
                            int fl = wc * 64 + n * 16 + laneM;
                            fb[L * 256 + (fl ^ ((L & 12) << 2))] = acc[m][n][j];
                        }
            }
            __syncthreads();
            // each wave stores 8 full rows; one nt instruction = 1KB contiguous
#pragma unroll
            for (int rr = 0; rr < 8; ++rr) {
                int R = wave * 8 + rr;
                int sx = (R & 12) << 2;
                f32x4 v = *reinterpret_cast<const f32x4*>(&fb[R * 256 + (l4 ^ sx)]);
                __builtin_nontemporal_store(
                    v, (f32x4*)(C + (size_t)(bm0 + p * 64 + R) * 2048 + bn0 + l4));
            }
        }
    }
}

// ---------------- launcher ----------------
extern "C" void kernel_launch(void* const* d_in, const int* in_sizes, int n_in,
                              void* d_out, int out_size, void* d_ws, size_t ws_size,
                              hipStream_t stream) {
    const float* entities  = (const float*)d_in[0];
    const float* relations = (const float*)d_in[1];
    const float* W         = (const float*)d_in[2];
    const float* b         = (const float*)d_in[3];

    char* ws = (char*)d_ws;
    unsigned short* W_bf = (unsigned short*)ws;
    unsigned short* X_bf = (unsigned short*)(ws + 524288);
    unsigned short* G_bf = (unsigned short*)(ws + 524288 + 2129920);
    unsigned short* Ap   = (unsigned short*)(ws + 524288 + 2129920 + 2129920);

    cast_all<<<1296, 256, 0, stream>>>(entities, relations, W, X_bf, W_bf);

    // gate GEMM: G[2080][512] = X @ W^T + b  (bf16 out)
    mfma_gemm_bt<true, true><<<17 * 4, 256, 0, stream>>>(
        X_bf, W_bf, b, (void*)G_bf, 2080, 512, 512);

    // A'[(e*32+r), d] = E[e,d] * R[r,d]
    build_ap<<<16384, 256, 0, stream>>>(G_bf, Ap);

    // main GEMM: out[65536][2048] = A' @ E^T  (128x256 tiles, 2 blocks/CU)
    gemm128x256<<<4096, 512, 0, stream>>>(Ap, G_bf, (float*)d_out);
}